// Round 2
// baseline (656.250 us; speedup 1.0000x reference)
//
#include <hip/hip_runtime.h>
#include <hip/hip_bf16.h>

typedef unsigned short u16;
typedef unsigned int   u32;

#define DCH  256
#define KCB  1024
#define HW   1024
#define NPOS 65536
#define MARGIN 0.12f

// ws layout (bytes)
#define ESQ_WS   0
#define IDX_WS   4096
#define FCNT_WS  266240
#define FLIST_WS 266304
#define XH_WS    1048576ull            // 65536*256 bf16 = 33.55 MB
#define EH_WS    34603008ull           // 1024*256 bf16 = 512 KB
#define EL_WS    35127296ull           // 512 KB  (total ws use ~35.7 MB)

using f32x4 = __attribute__((ext_vector_type(4))) float;
using s16x8 = __attribute__((ext_vector_type(8))) short;

__device__ __forceinline__ u16 f2bf(float x) {
    __hip_bfloat16 h = __float2bfloat16(x);
    return *reinterpret_cast<u16*>(&h);
}
__device__ __forceinline__ float bf2f(u16 u) {
    __hip_bfloat16 h;
    *reinterpret_cast<u16*>(&h) = u;
    return __bfloat162float(h);
}

__device__ __forceinline__ void gl_lds16(const void* g, void* l) {
    __builtin_amdgcn_global_load_lds(
        (const __attribute__((address_space(1))) void*)g,
        (__attribute__((address_space(3))) void*)l, 16, 0, 0);
}

// ---------------- prep: transpose [256][1024] -> [1024][256] per batch, split to bf16 hi(/lo)
__global__ __launch_bounds__(256) void prep_split(const float* __restrict__ src,
                                                  u16* __restrict__ dH,
                                                  u16* __restrict__ dL,
                                                  int hasLo) {
    __shared__ u16 HS[32][128];
    __shared__ u16 LS[32][128];
    const int tid = threadIdx.x;
    const int b = blockIdx.x >> 3;
    const int p0 = (blockIdx.x & 7) * 128;
    const size_t nbase = (size_t)b * 1024 + p0;
    for (int cc = 0; cc < 8; ++cc) {
#pragma unroll
        for (int r = 0; r < 4; ++r) {
            int id4 = tid + 256 * r;          // float4 unit over [32 c][128 p]
            int c = id4 >> 5;
            int pq = id4 & 31;
            float4 v = *reinterpret_cast<const float4*>(
                src + (size_t)b * 262144 + (size_t)(cc * 32 + c) * 1024 + p0 + pq * 4);
            u16 h0 = f2bf(v.x), h1 = f2bf(v.y), h2 = f2bf(v.z), h3 = f2bf(v.w);
            uint2 hp; hp.x = (u32)h0 | ((u32)h1 << 16); hp.y = (u32)h2 | ((u32)h3 << 16);
            *reinterpret_cast<uint2*>(&HS[c][pq * 4]) = hp;
            u16 l0 = f2bf(v.x - bf2f(h0)), l1 = f2bf(v.y - bf2f(h1));
            u16 l2 = f2bf(v.z - bf2f(h2)), l3 = f2bf(v.w - bf2f(h3));
            uint2 lp; lp.x = (u32)l0 | ((u32)l1 << 16); lp.y = (u32)l2 | ((u32)l3 << 16);
            *reinterpret_cast<uint2*>(&LS[c][pq * 4]) = lp;
        }
        __syncthreads();
#pragma unroll
        for (int r = 0; r < 4; ++r) {
            int id = tid + 256 * r;           // 4-d chunk over [128 p][8 g]
            int p = id >> 3;
            int g = id & 7;
            uint2 oh;
            oh.x = (u32)HS[g * 4 + 0][p] | ((u32)HS[g * 4 + 1][p] << 16);
            oh.y = (u32)HS[g * 4 + 2][p] | ((u32)HS[g * 4 + 3][p] << 16);
            *reinterpret_cast<uint2*>(dH + (nbase + p) * 256 + cc * 32 + g * 4) = oh;
            if (hasLo) {
                uint2 ol;
                ol.x = (u32)LS[g * 4 + 0][p] | ((u32)LS[g * 4 + 1][p] << 16);
                ol.y = (u32)LS[g * 4 + 2][p] | ((u32)LS[g * 4 + 3][p] << 16);
                *reinterpret_cast<uint2*>(dL + (nbase + p) * 256 + cc * 32 + g * 4) = ol;
            }
        }
        __syncthreads();
    }
}

__global__ __launch_bounds__(256) void esq_kernel(const float* __restrict__ E,
                                                  float* __restrict__ esq) {
    int k = blockIdx.x * 256 + threadIdx.x;
    float s = 0.f;
#pragma unroll 8
    for (int c = 0; c < DCH; ++c) {
        float e = E[c * KCB + k];
        s = fmaf(e, e, s);
    }
    esq[k] = s;
}

// ---------------- main: split-bf16 MFMA distance + fused top-2 argmin
#define BUFS  24576
#define EH_O  8192
#define EL_O  16384
#define ESQ_O 49152
#define MRG_O 53248
#define SM_SZ 56320

__global__ __launch_bounds__(256, 2) void vq_main_mfma(
        const u16* __restrict__ XhG, const u16* __restrict__ EhG,
        const u16* __restrict__ ElG, const float* __restrict__ esq,
        int* __restrict__ idx_out, int* __restrict__ flag_cnt,
        int* __restrict__ flag_list) {
    __shared__ alignas(16) char sm[SM_SZ];
    const int tid = threadIdx.x;
    const int l = tid & 63;
    const int w = tid >> 6;
    const int wm = w >> 1, wn = w & 1;
    const int pbase = blockIdx.x * 128;

    // esq -> LDS (covered by prologue barrier)
    *reinterpret_cast<float4*>(sm + ESQ_O + tid * 16) =
        *reinterpret_cast<const float4*>(esq + tid * 4);

    // staging constants: granule g = (w*2+q)*64 + l ; row = g>>2 ; s_lin = l&3
    const int rowt0 = w * 32 + (l >> 2);
    const int slog = (l & 3) ^ ((rowt0 >> 1) & 3);       // same for q=0,1 (row+16)
    const char* XhB = reinterpret_cast<const char*>(XhG);
    const char* EhB = reinterpret_cast<const char*>(EhG);
    const char* ElB = reinterpret_cast<const char*>(ElG);
    const size_t xoff0 = (size_t)(pbase + rowt0) * 512 + slog * 16;
    const size_t eoff0 = (size_t)rowt0 * 512 + slog * 16;
    const int w2k = (w * 2) * 1024;

    // fragment read addresses (XOR slot swizzle -> 2-way (free) bank pattern)
    const int rA = wm * 64 + (l & 15);
    const int addrA = rA * 64 + (((l >> 4) ^ ((rA >> 1) & 3)) * 16);
    const int rB = wn * 64 + (l & 15);
    const int addrB = rB * 64 + (((l >> 4) ^ ((rB >> 1) & 3)) * 16);

    auto STAGE = [&](int bufo, int nt, int dt) {
        size_t xo = xoff0 + (size_t)dt * 64;
        gl_lds16(XhB + xo,        sm + bufo + w2k);
        gl_lds16(XhB + xo + 8192, sm + bufo + w2k + 1024);
        size_t eo = eoff0 + (size_t)nt * 65536 + (size_t)dt * 64;
        gl_lds16(EhB + eo,        sm + bufo + EH_O + w2k);
        gl_lds16(EhB + eo + 8192, sm + bufo + EH_O + w2k + 1024);
        gl_lds16(ElB + eo,        sm + bufo + EL_O + w2k);
        gl_lds16(ElB + eo + 8192, sm + bufo + EL_O + w2k + 1024);
    };

    float b1[16], b2[16];
    int   i1[16];
#pragma unroll
    for (int q = 0; q < 16; ++q) { b1[q] = 3.4e38f; b2[q] = 3.4e38f; i1[q] = 0; }

    STAGE(0, 0, 0);
    __syncthreads();

    int step = 0;
    for (int nt = 0; nt < 8; ++nt) {
        f32x4 acc[4][4];
#pragma unroll
        for (int i = 0; i < 4; ++i)
#pragma unroll
            for (int j = 0; j < 4; ++j)
#pragma unroll
                for (int r = 0; r < 4; ++r) acc[i][j][r] = 0.f;

        for (int dt = 0; dt < 8; ++dt) {
            int nxt = step + 1;
            if (nxt < 64) STAGE((nxt & 1) * BUFS, nxt >> 3, nxt & 7);
            const char* bo = sm + (step & 1) * BUFS;
            s16x8 a[4], bh[4], bl[4];
#pragma unroll
            for (int i = 0; i < 4; ++i)
                a[i] = *reinterpret_cast<const s16x8*>(bo + addrA + i * 1024);
#pragma unroll
            for (int j = 0; j < 4; ++j) {
                bh[j] = *reinterpret_cast<const s16x8*>(bo + EH_O + addrB + j * 1024);
                bl[j] = *reinterpret_cast<const s16x8*>(bo + EL_O + addrB + j * 1024);
            }
#pragma unroll
            for (int i = 0; i < 4; ++i)
#pragma unroll
                for (int j = 0; j < 4; ++j) {
                    acc[i][j] = __builtin_amdgcn_mfma_f32_16x16x32_bf16(a[i], bh[j], acc[i][j], 0, 0, 0);
                    acc[i][j] = __builtin_amdgcn_mfma_f32_16x16x32_bf16(a[i], bl[j], acc[i][j], 0, 0, 0);
                }
            __syncthreads();
            ++step;
        }

        // epilogue: dist = esq - 2S, branchless running top-2
        const int kb = nt * 128 + wn * 64 + (l & 15);
        float eq[4];
#pragma unroll
        for (int j = 0; j < 4; ++j)
            eq[j] = *reinterpret_cast<const float*>(sm + ESQ_O + (kb + j * 16) * 4);
#pragma unroll
        for (int i = 0; i < 4; ++i)
#pragma unroll
            for (int j = 0; j < 4; ++j)
#pragma unroll
                for (int r = 0; r < 4; ++r) {
                    float s = fmaf(-2.f, acc[i][j][r], eq[j]);
                    int ri = i * 4 + r;
                    bool lt = s < b1[ri];
                    b2[ri] = fminf(b2[ri], fmaxf(s, b1[ri]));
                    i1[ri] = lt ? (kb + j * 16) : i1[ri];
                    b1[ri] = fminf(b1[ri], s);
                }
    }

    // cross-lane top-2 merge over the 16 col-lanes
#pragma unroll
    for (int m = 1; m <= 8; m <<= 1) {
#pragma unroll
        for (int q = 0; q < 16; ++q) {
            float ob1 = __shfl_xor(b1[q], m);
            float ob2 = __shfl_xor(b2[q], m);
            int   oi  = __shfl_xor(i1[q], m);
            bool lt = ob1 < b1[q];
            b2[q] = fminf(fminf(b2[q], ob2), fmaxf(b1[q], ob1));
            i1[q] = lt ? oi : i1[q];
            b1[q] = fminf(b1[q], ob1);
        }
    }

    if ((l & 15) == 0) {
#pragma unroll
        for (int i = 0; i < 4; ++i)
#pragma unroll
            for (int r = 0; r < 4; ++r) {
                int q = i * 4 + r;
                int rl = wm * 64 + i * 16 + (l >> 4) * 4 + r;
                *reinterpret_cast<float*>(sm + MRG_O + (rl * 2 + wn) * 4) = b1[q];
                *reinterpret_cast<float*>(sm + MRG_O + 1024 + (rl * 2 + wn) * 4) = b2[q];
                *reinterpret_cast<int*>(sm + MRG_O + 2048 + (rl * 2 + wn) * 4) = i1[q];
            }
    }
    __syncthreads();
    if (tid < 128) {
        float a1 = *reinterpret_cast<float*>(sm + MRG_O + (tid * 2 + 0) * 4);
        float a2 = *reinterpret_cast<float*>(sm + MRG_O + 1024 + (tid * 2 + 0) * 4);
        int   ai = *reinterpret_cast<int*>(sm + MRG_O + 2048 + (tid * 2 + 0) * 4);
        float c1 = *reinterpret_cast<float*>(sm + MRG_O + (tid * 2 + 1) * 4);
        float c2 = *reinterpret_cast<float*>(sm + MRG_O + 1024 + (tid * 2 + 1) * 4);
        int   ci = *reinterpret_cast<int*>(sm + MRG_O + 2048 + (tid * 2 + 1) * 4);
        bool lt = c1 < a1;
        float B1 = fminf(a1, c1);
        float B2 = fminf(fminf(a2, c2), fmaxf(a1, c1));
        int I1 = lt ? ci : ai;
        int n = pbase + tid;
        idx_out[n] = I1;
        if (B2 - B1 < MARGIN) {
            int s2 = atomicAdd(flag_cnt, 1);
            flag_list[s2] = n;
        }
    }
}

// ---------------- exact fp64 re-scan for flagged near-ties
__global__ __launch_bounds__(256) void vq_repair(const float* __restrict__ X,
                                                 const float* __restrict__ E,
                                                 int* __restrict__ idx_out,
                                                 const int* __restrict__ flag_cnt,
                                                 const int* __restrict__ flag_list) {
    __shared__ double xs[256];
    __shared__ double rd[256];
    __shared__ int    ri[256];
    const int tid = threadIdx.x;
    int cnt = *flag_cnt;
    for (int f = blockIdx.x; f < cnt; f += gridDim.x) {
        int n = flag_list[f];
        int b = n >> 10, pos = n & 1023;
        xs[tid] = (double)X[(size_t)b * (DCH * HW) + (size_t)tid * HW + pos];
        __syncthreads();
        double best = 1e300;
        int bi = KCB;
        for (int kk = 0; kk < 4; ++kk) {
            int k = kk * 256 + tid;
            double s = 0.0, eqd = 0.0;
#pragma unroll 4
            for (int c = 0; c < DCH; ++c) {
                double e = (double)E[c * KCB + k];
                eqd = fma(e, e, eqd);
                s   = fma(xs[c], e, s);
            }
            double d = eqd - 2.0 * s;
            if (d < best || (d == best && k < bi)) { best = d; bi = k; }
        }
        rd[tid] = best; ri[tid] = bi;
        __syncthreads();
        for (int off = 128; off > 0; off >>= 1) {
            if (tid < off) {
                double od = rd[tid + off]; int oi = ri[tid + off];
                if (od < rd[tid] || (od == rd[tid] && oi < ri[tid])) { rd[tid] = od; ri[tid] = oi; }
            }
            __syncthreads();
        }
        if (tid == 0) idx_out[n] = ri[0];
        __syncthreads();
    }
}

// ---------------- gather + write outputs
__global__ __launch_bounds__(256) void vq_write(const float* __restrict__ E,
                                                const int* __restrict__ idx_ws,
                                                float* __restrict__ out0,
                                                float* __restrict__ out1,
                                                float* __restrict__ out2) {
    __shared__ int kk[1024];
    const int tid = threadIdx.x;
    const int b = blockIdx.x >> 3;
    const int cch = blockIdx.x & 7;
#pragma unroll
    for (int r = 0; r < 4; ++r) kk[tid + 256 * r] = idx_ws[b * HW + tid + 256 * r];
    __syncthreads();
    int p0 = tid * 4;
    if (cch == 0) {
        float4 v = {(float)kk[p0], (float)kk[p0 + 1], (float)kk[p0 + 2], (float)kk[p0 + 3]};
        *reinterpret_cast<float4*>(out2 + b * HW + p0) = v;
    }
    int k0 = kk[p0], k1 = kk[p0 + 1], k2 = kk[p0 + 2], k3 = kk[p0 + 3];
    for (int c = cch * 32; c < cch * 32 + 32; ++c) {
        const float* Er = E + (size_t)c * KCB;
        float4 v = {Er[k0], Er[k1], Er[k2], Er[k3]};
        size_t o = (size_t)b * (DCH * HW) + (size_t)c * HW + p0;
        *reinterpret_cast<float4*>(out0 + o) = v;
        *reinterpret_cast<float4*>(out1 + o) = v;
    }
}

extern "C" void kernel_launch(void* const* d_in, const int* in_sizes, int n_in,
                              void* d_out, int out_size, void* d_ws, size_t ws_size,
                              hipStream_t stream) {
    const float* X = (const float*)d_in[0];   // [64,256,32,32] fp32
    const float* E = (const float*)d_in[1];   // [256,1024] fp32
    float* out = (float*)d_out;
    char* ws = (char*)d_ws;

    float* esq = (float*)(ws + ESQ_WS);
    int* idx   = (int*)(ws + IDX_WS);
    int* fcnt  = (int*)(ws + FCNT_WS);
    int* flist = (int*)(ws + FLIST_WS);
    u16* Xh    = (u16*)(ws + XH_WS);
    u16* Eh    = (u16*)(ws + EH_WS);
    u16* El    = (u16*)(ws + EL_WS);

    hipMemsetAsync(fcnt, 0, 4, stream);
    prep_split<<<512, 256, 0, stream>>>(X, Xh, nullptr, 0);
    prep_split<<<8, 256, 0, stream>>>(E, Eh, El, 1);
    esq_kernel<<<4, 256, 0, stream>>>(E, esq);
    vq_main_mfma<<<512, 256, 0, stream>>>(Xh, Eh, El, esq, idx, fcnt, flist);
    vq_repair<<<256, 256, 0, stream>>>(X, E, idx, fcnt, flist);
    vq_write<<<512, 256, 0, stream>>>(E, idx,
                                      out,                // q_ste
                                      out + 16777216,     // quantized
                                      out + 33554432);    // indices (as float)
}

// Round 3
// 247.796 us; speedup vs baseline: 2.6483x; 2.6483x over previous
//
#include <hip/hip_runtime.h>
#include <hip/hip_bf16.h>

typedef unsigned short u16;
typedef unsigned int   u32;

#define DCH  256
#define KCB  1024
#define HW   1024
#define NPOS 65536
#define MARGIN 0.12f

// ws layout (bytes)
#define ESQ_WS   0
#define IDX_WS   4096
#define FCNT_WS  266240
#define FLIST_WS 266304
#define ESQD_WS  528448ull             // double[1024] = 8 KB
#define XH_WS    1048576ull            // 65536*256 bf16 = 33.55 MB
#define EH_WS    34603008ull           // 1024*256 bf16 = 512 KB
#define EL_WS    35127296ull           // 512 KB  (total ws use ~35.7 MB)

using f32x4 = __attribute__((ext_vector_type(4))) float;
using s16x8 = __attribute__((ext_vector_type(8))) short;

__device__ __forceinline__ u16 f2bf(float x) {
    __hip_bfloat16 h = __float2bfloat16(x);
    return *reinterpret_cast<u16*>(&h);
}
__device__ __forceinline__ float bf2f(u16 u) {
    __hip_bfloat16 h;
    *reinterpret_cast<u16*>(&h) = u;
    return __bfloat162float(h);
}

__device__ __forceinline__ void gl_lds16(const void* g, void* l) {
    __builtin_amdgcn_global_load_lds(
        (const __attribute__((address_space(1))) void*)g,
        (__attribute__((address_space(3))) void*)l, 16, 0, 0);
}

// ---------------- prep: transpose [256][1024] -> [1024][256] per batch, split to bf16 hi(/lo)
__global__ __launch_bounds__(256) void prep_split(const float* __restrict__ src,
                                                  u16* __restrict__ dH,
                                                  u16* __restrict__ dL,
                                                  int hasLo) {
    __shared__ u16 HS[32][128];
    __shared__ u16 LS[32][128];
    const int tid = threadIdx.x;
    const int b = blockIdx.x >> 3;
    const int p0 = (blockIdx.x & 7) * 128;
    const size_t nbase = (size_t)b * 1024 + p0;
    for (int cc = 0; cc < 8; ++cc) {
#pragma unroll
        for (int r = 0; r < 4; ++r) {
            int id4 = tid + 256 * r;          // float4 unit over [32 c][128 p]
            int c = id4 >> 5;
            int pq = id4 & 31;
            float4 v = *reinterpret_cast<const float4*>(
                src + (size_t)b * 262144 + (size_t)(cc * 32 + c) * 1024 + p0 + pq * 4);
            u16 h0 = f2bf(v.x), h1 = f2bf(v.y), h2 = f2bf(v.z), h3 = f2bf(v.w);
            uint2 hp; hp.x = (u32)h0 | ((u32)h1 << 16); hp.y = (u32)h2 | ((u32)h3 << 16);
            *reinterpret_cast<uint2*>(&HS[c][pq * 4]) = hp;
            u16 l0 = f2bf(v.x - bf2f(h0)), l1 = f2bf(v.y - bf2f(h1));
            u16 l2 = f2bf(v.z - bf2f(h2)), l3 = f2bf(v.w - bf2f(h3));
            uint2 lp; lp.x = (u32)l0 | ((u32)l1 << 16); lp.y = (u32)l2 | ((u32)l3 << 16);
            *reinterpret_cast<uint2*>(&LS[c][pq * 4]) = lp;
        }
        __syncthreads();
#pragma unroll
        for (int r = 0; r < 4; ++r) {
            int id = tid + 256 * r;           // 4-d chunk over [128 p][8 g]
            int p = id >> 3;
            int g = id & 7;
            uint2 oh;
            oh.x = (u32)HS[g * 4 + 0][p] | ((u32)HS[g * 4 + 1][p] << 16);
            oh.y = (u32)HS[g * 4 + 2][p] | ((u32)HS[g * 4 + 3][p] << 16);
            *reinterpret_cast<uint2*>(dH + (nbase + p) * 256 + cc * 32 + g * 4) = oh;
            if (hasLo) {
                uint2 ol;
                ol.x = (u32)LS[g * 4 + 0][p] | ((u32)LS[g * 4 + 1][p] << 16);
                ol.y = (u32)LS[g * 4 + 2][p] | ((u32)LS[g * 4 + 3][p] << 16);
                *reinterpret_cast<uint2*>(dL + (nbase + p) * 256 + cc * 32 + g * 4) = ol;
            }
        }
        __syncthreads();
    }
}

// esq in fp32 (for main) and fp64 (for repair)
__global__ __launch_bounds__(256) void esq_kernel(const float* __restrict__ E,
                                                  float* __restrict__ esq,
                                                  double* __restrict__ esqd) {
    int k = blockIdx.x * 256 + threadIdx.x;
    double s = 0.0;
#pragma unroll 8
    for (int c = 0; c < DCH; ++c) {
        double e = (double)E[c * KCB + k];
        s = fma(e, e, s);
    }
    esq[k] = (float)s;
    esqd[k] = s;
}

// ---------------- main: split-bf16 MFMA distance + fused top-2 argmin
#define BUFS  24576
#define EH_O  8192
#define EL_O  16384
#define ESQ_O 49152
#define MRG_O 53248
#define SM_SZ 56320

__global__ __launch_bounds__(256, 2) void vq_main_mfma(
        const u16* __restrict__ XhG, const u16* __restrict__ EhG,
        const u16* __restrict__ ElG, const float* __restrict__ esq,
        int* __restrict__ idx_out, int* __restrict__ flag_cnt,
        int* __restrict__ flag_list) {
    __shared__ alignas(16) char sm[SM_SZ];
    const int tid = threadIdx.x;
    const int l = tid & 63;
    const int w = tid >> 6;
    const int wm = w >> 1, wn = w & 1;
    const int pbase = blockIdx.x * 128;

    *reinterpret_cast<float4*>(sm + ESQ_O + tid * 16) =
        *reinterpret_cast<const float4*>(esq + tid * 4);

    const int rowt0 = w * 32 + (l >> 2);
    const int slog = (l & 3) ^ ((rowt0 >> 1) & 3);
    const char* XhB = reinterpret_cast<const char*>(XhG);
    const char* EhB = reinterpret_cast<const char*>(EhG);
    const char* ElB = reinterpret_cast<const char*>(ElG);
    const size_t xoff0 = (size_t)(pbase + rowt0) * 512 + slog * 16;
    const size_t eoff0 = (size_t)rowt0 * 512 + slog * 16;
    const int w2k = (w * 2) * 1024;

    const int rA = wm * 64 + (l & 15);
    const int addrA = rA * 64 + (((l >> 4) ^ ((rA >> 1) & 3)) * 16);
    const int rB = wn * 64 + (l & 15);
    const int addrB = rB * 64 + (((l >> 4) ^ ((rB >> 1) & 3)) * 16);

    auto STAGE = [&](int bufo, int nt, int dt) {
        size_t xo = xoff0 + (size_t)dt * 64;
        gl_lds16(XhB + xo,        sm + bufo + w2k);
        gl_lds16(XhB + xo + 8192, sm + bufo + w2k + 1024);
        size_t eo = eoff0 + (size_t)nt * 65536 + (size_t)dt * 64;
        gl_lds16(EhB + eo,        sm + bufo + EH_O + w2k);
        gl_lds16(EhB + eo + 8192, sm + bufo + EH_O + w2k + 1024);
        gl_lds16(ElB + eo,        sm + bufo + EL_O + w2k);
        gl_lds16(ElB + eo + 8192, sm + bufo + EL_O + w2k + 1024);
    };

    float b1[16], b2[16];
    int   i1[16];
#pragma unroll
    for (int q = 0; q < 16; ++q) { b1[q] = 3.4e38f; b2[q] = 3.4e38f; i1[q] = 0; }

    STAGE(0, 0, 0);
    __syncthreads();

    int step = 0;
    for (int nt = 0; nt < 8; ++nt) {
        f32x4 acc[4][4];
#pragma unroll
        for (int i = 0; i < 4; ++i)
#pragma unroll
            for (int j = 0; j < 4; ++j)
#pragma unroll
                for (int r = 0; r < 4; ++r) acc[i][j][r] = 0.f;

        for (int dt = 0; dt < 8; ++dt) {
            int nxt = step + 1;
            if (nxt < 64) STAGE((nxt & 1) * BUFS, nxt >> 3, nxt & 7);
            const char* bo = sm + (step & 1) * BUFS;
            s16x8 a[4], bh[4], bl[4];
#pragma unroll
            for (int i = 0; i < 4; ++i)
                a[i] = *reinterpret_cast<const s16x8*>(bo + addrA + i * 1024);
#pragma unroll
            for (int j = 0; j < 4; ++j) {
                bh[j] = *reinterpret_cast<const s16x8*>(bo + EH_O + addrB + j * 1024);
                bl[j] = *reinterpret_cast<const s16x8*>(bo + EL_O + addrB + j * 1024);
            }
#pragma unroll
            for (int i = 0; i < 4; ++i)
#pragma unroll
                for (int j = 0; j < 4; ++j) {
                    acc[i][j] = __builtin_amdgcn_mfma_f32_16x16x32_bf16(a[i], bh[j], acc[i][j], 0, 0, 0);
                    acc[i][j] = __builtin_amdgcn_mfma_f32_16x16x32_bf16(a[i], bl[j], acc[i][j], 0, 0, 0);
                }
            __syncthreads();
            ++step;
        }

        const int kb = nt * 128 + wn * 64 + (l & 15);
        float eq[4];
#pragma unroll
        for (int j = 0; j < 4; ++j)
            eq[j] = *reinterpret_cast<const float*>(sm + ESQ_O + (kb + j * 16) * 4);
#pragma unroll
        for (int i = 0; i < 4; ++i)
#pragma unroll
            for (int j = 0; j < 4; ++j)
#pragma unroll
                for (int r = 0; r < 4; ++r) {
                    float s = fmaf(-2.f, acc[i][j][r], eq[j]);
                    int ri = i * 4 + r;
                    bool lt = s < b1[ri];
                    b2[ri] = fminf(b2[ri], fmaxf(s, b1[ri]));
                    i1[ri] = lt ? (kb + j * 16) : i1[ri];
                    b1[ri] = fminf(b1[ri], s);
                }
    }

#pragma unroll
    for (int m = 1; m <= 8; m <<= 1) {
#pragma unroll
        for (int q = 0; q < 16; ++q) {
            float ob1 = __shfl_xor(b1[q], m);
            float ob2 = __shfl_xor(b2[q], m);
            int   oi  = __shfl_xor(i1[q], m);
            bool lt = ob1 < b1[q];
            b2[q] = fminf(fminf(b2[q], ob2), fmaxf(b1[q], ob1));
            i1[q] = lt ? oi : i1[q];
            b1[q] = fminf(b1[q], ob1);
        }
    }

    if ((l & 15) == 0) {
#pragma unroll
        for (int i = 0; i < 4; ++i)
#pragma unroll
            for (int r = 0; r < 4; ++r) {
                int q = i * 4 + r;
                int rl = wm * 64 + i * 16 + (l >> 4) * 4 + r;
                *reinterpret_cast<float*>(sm + MRG_O + (rl * 2 + wn) * 4) = b1[q];
                *reinterpret_cast<float*>(sm + MRG_O + 1024 + (rl * 2 + wn) * 4) = b2[q];
                *reinterpret_cast<int*>(sm + MRG_O + 2048 + (rl * 2 + wn) * 4) = i1[q];
            }
    }
    __syncthreads();
    if (tid < 128) {
        float a1 = *reinterpret_cast<float*>(sm + MRG_O + (tid * 2 + 0) * 4);
        float a2 = *reinterpret_cast<float*>(sm + MRG_O + 1024 + (tid * 2 + 0) * 4);
        int   ai = *reinterpret_cast<int*>(sm + MRG_O + 2048 + (tid * 2 + 0) * 4);
        float c1 = *reinterpret_cast<float*>(sm + MRG_O + (tid * 2 + 1) * 4);
        float c2 = *reinterpret_cast<float*>(sm + MRG_O + 1024 + (tid * 2 + 1) * 4);
        int   ci = *reinterpret_cast<int*>(sm + MRG_O + 2048 + (tid * 2 + 1) * 4);
        bool lt = c1 < a1;
        float B1 = fminf(a1, c1);
        float B2 = fminf(fminf(a2, c2), fmaxf(a1, c1));
        int I1 = lt ? ci : ai;
        int n = pbase + tid;
        idx_out[n] = I1;
        if (B2 - B1 < MARGIN) {
            int s2 = atomicAdd(flag_cnt, 1);
            flag_list[s2] = n;
        }
    }
}

// ---------------- exact fp64 re-scan, 4 flags per block, parallel
#define RFPB 4
__global__ __launch_bounds__(256) void vq_repair(const float* __restrict__ X,
                                                 const float* __restrict__ E,
                                                 const double* __restrict__ esqd,
                                                 int* __restrict__ idx_out,
                                                 const int* __restrict__ flag_cnt,
                                                 const int* __restrict__ flag_list) {
    __shared__ double xs[RFPB][256];
    __shared__ double rd[RFPB][256];
    __shared__ int    ri[RFPB][256];
    const int tid = threadIdx.x;
    const int cnt = *flag_cnt;
    for (int f0 = blockIdx.x * RFPB; f0 < cnt; f0 += gridDim.x * RFPB) {
        // stage the RFPB flagged x-columns into LDS (fp64)
#pragma unroll
        for (int g = 0; g < RFPB; ++g) {
            int f = f0 + g;
            int n = flag_list[f < cnt ? f : f0];
            int b = n >> 10, p = n & 1023;
            xs[g][tid] = (double)X[(size_t)b * 262144 + (size_t)tid * 1024 + p];
        }
        __syncthreads();
        double s[RFPB][4];
#pragma unroll
        for (int g = 0; g < RFPB; ++g)
#pragma unroll
            for (int j = 0; j < 4; ++j) s[g][j] = 0.0;
        const float4* Erow = reinterpret_cast<const float4*>(E) + tid;   // E[c][tid*4]
#pragma unroll 2
        for (int c = 0; c < 256; ++c) {
            float4 ev = Erow[c * 256];
            double e0 = (double)ev.x, e1 = (double)ev.y, e2 = (double)ev.z, e3 = (double)ev.w;
#pragma unroll
            for (int g = 0; g < RFPB; ++g) {
                double xv = xs[g][c];
                s[g][0] = fma(xv, e0, s[g][0]);
                s[g][1] = fma(xv, e1, s[g][1]);
                s[g][2] = fma(xv, e2, s[g][2]);
                s[g][3] = fma(xv, e3, s[g][3]);
            }
        }
        const int k0 = tid * 4;
        const double eq0 = esqd[k0], eq1 = esqd[k0 + 1], eq2 = esqd[k0 + 2], eq3 = esqd[k0 + 3];
#pragma unroll
        for (int g = 0; g < RFPB; ++g) {
            double d0 = eq0 - 2.0 * s[g][0];
            double d1 = eq1 - 2.0 * s[g][1];
            double d2 = eq2 - 2.0 * s[g][2];
            double d3 = eq3 - 2.0 * s[g][3];
            double bd = d0; int bi = k0;
            if (d1 < bd) { bd = d1; bi = k0 + 1; }
            if (d2 < bd) { bd = d2; bi = k0 + 2; }
            if (d3 < bd) { bd = d3; bi = k0 + 3; }
            rd[g][tid] = bd; ri[g][tid] = bi;
        }
        __syncthreads();
        for (int off = 128; off > 0; off >>= 1) {
            if (tid < off) {
#pragma unroll
                for (int g = 0; g < RFPB; ++g) {
                    double od = rd[g][tid + off]; int oi = ri[g][tid + off];
                    if (od < rd[g][tid] || (od == rd[g][tid] && oi < ri[g][tid])) {
                        rd[g][tid] = od; ri[g][tid] = oi;
                    }
                }
            }
            __syncthreads();
        }
        if (tid < RFPB && (f0 + tid) < cnt) {
            idx_out[flag_list[f0 + tid]] = ri[tid][0];
        }
        __syncthreads();
    }
}

// ---------------- gather + write outputs
__global__ __launch_bounds__(256) void vq_write(const float* __restrict__ E,
                                                const int* __restrict__ idx_ws,
                                                float* __restrict__ out0,
                                                float* __restrict__ out1,
                                                float* __restrict__ out2) {
    __shared__ int kk[1024];
    const int tid = threadIdx.x;
    const int b = blockIdx.x >> 3;
    const int cch = blockIdx.x & 7;
#pragma unroll
    for (int r = 0; r < 4; ++r) kk[tid + 256 * r] = idx_ws[b * HW + tid + 256 * r];
    __syncthreads();
    int p0 = tid * 4;
    if (cch == 0) {
        float4 v = {(float)kk[p0], (float)kk[p0 + 1], (float)kk[p0 + 2], (float)kk[p0 + 3]};
        *reinterpret_cast<float4*>(out2 + b * HW + p0) = v;
    }
    int k0 = kk[p0], k1 = kk[p0 + 1], k2 = kk[p0 + 2], k3 = kk[p0 + 3];
    for (int c = cch * 32; c < cch * 32 + 32; ++c) {
        const float* Er = E + (size_t)c * KCB;
        float4 v = {Er[k0], Er[k1], Er[k2], Er[k3]};
        size_t o = (size_t)b * (DCH * HW) + (size_t)c * HW + p0;
        *reinterpret_cast<float4*>(out0 + o) = v;
        *reinterpret_cast<float4*>(out1 + o) = v;
    }
}

extern "C" void kernel_launch(void* const* d_in, const int* in_sizes, int n_in,
                              void* d_out, int out_size, void* d_ws, size_t ws_size,
                              hipStream_t stream) {
    const float* X = (const float*)d_in[0];   // [64,256,32,32] fp32
    const float* E = (const float*)d_in[1];   // [256,1024] fp32
    float* out = (float*)d_out;
    char* ws = (char*)d_ws;

    float* esq   = (float*)(ws + ESQ_WS);
    int* idx     = (int*)(ws + IDX_WS);
    int* fcnt    = (int*)(ws + FCNT_WS);
    int* flist   = (int*)(ws + FLIST_WS);
    double* esqd = (double*)(ws + ESQD_WS);
    u16* Xh      = (u16*)(ws + XH_WS);
    u16* Eh      = (u16*)(ws + EH_WS);
    u16* El      = (u16*)(ws + EL_WS);

    hipMemsetAsync(fcnt, 0, 4, stream);
    prep_split<<<512, 256, 0, stream>>>(X, Xh, nullptr, 0);
    prep_split<<<8, 256, 0, stream>>>(E, Eh, El, 1);
    esq_kernel<<<4, 256, 0, stream>>>(E, esq, esqd);
    vq_main_mfma<<<512, 256, 0, stream>>>(Xh, Eh, El, esq, idx, fcnt, flist);
    vq_repair<<<1024, 256, 0, stream>>>(X, E, esqd, idx, fcnt, flist);
    vq_write<<<512, 256, 0, stream>>>(E, idx,
                                      out,                // q_ste
                                      out + 16777216,     // quantized
                                      out + 33554432);    // indices (as float)
}

// Round 4
// 208.545 us; speedup vs baseline: 3.1468x; 1.1882x over previous
//
#include <hip/hip_runtime.h>
#include <hip/hip_bf16.h>

typedef unsigned short u16;
typedef unsigned int   u32;

#define DCH  256
#define KCB  1024
#define HW   1024
#define NPOS 65536
#define MARGIN 0.12f

// ws layout (bytes)
#define ESQ_WS   0
#define IDX_WS   4096
#define FCNT_WS  266240
#define FLIST_WS 266304
#define ESQD_WS  528448ull             // double[1024] = 8 KB
#define XH_WS    1048576ull            // 65536*256 bf16 = 33.55 MB
#define EH_WS    34603008ull           // 1024*256 bf16 = 512 KB
#define EL_WS    35127296ull           // 512 KB  (total ws use ~35.7 MB)

using f32x4 = __attribute__((ext_vector_type(4))) float;
using s16x8 = __attribute__((ext_vector_type(8))) short;

__device__ __forceinline__ u16 f2bf(float x) {
    __hip_bfloat16 h = __float2bfloat16(x);
    return *reinterpret_cast<u16*>(&h);
}
__device__ __forceinline__ float bf2f(u16 u) {
    __hip_bfloat16 h;
    *reinterpret_cast<u16*>(&h) = u;
    return __bfloat162float(h);
}

__device__ __forceinline__ void gl_lds16(const void* g, void* l) {
    __builtin_amdgcn_global_load_lds(
        (const __attribute__((address_space(1))) void*)g,
        (__attribute__((address_space(3))) void*)l, 16, 0, 0);
}

// ---------------- prep X: transpose [256 c][1024 p] -> Xh[n][256 d] bf16
// fp32 padded-LDS transpose, bank-conflict-free.
__global__ __launch_bounds__(256) void prep_x(const float* __restrict__ X,
                                              u16* __restrict__ Xh) {
    __shared__ float Xs[32][260];     // pad 260 -> bank (c*4 + p) % 32
    const int tid = threadIdx.x;
    const int b  = blockIdx.x >> 5;         // 0..63
    const int pc = (blockIdx.x >> 3) & 3;   // 0..3
    const int cc = blockIdx.x & 7;          // 0..7
    const int p0 = pc * 256;
    const int c0 = cc * 32;
    const size_t nbase = (size_t)b * 1024 + p0;

    // stage [32 c][256 p] fp32, coalesced
#pragma unroll
    for (int r = 0; r < 8; ++r) {
        int id4 = tid + 256 * r;            // float4 id over [32][64]
        int c = id4 >> 6;
        int q = id4 & 63;
        float4 v = *reinterpret_cast<const float4*>(
            X + (size_t)b * 262144 + (size_t)(c0 + c) * 1024 + p0 + q * 4);
        *reinterpret_cast<float4*>(&Xs[c][q * 4]) = v;
    }
    __syncthreads();

    // transpose-read: thread t -> position p = t, produce 32 d's (4 x 16B)
    const int p = tid;
#pragma unroll
    for (int dg = 0; dg < 4; ++dg) {
        u32 w0, w1, w2, w3;
        {
            float f0 = Xs[dg * 8 + 0][p], f1 = Xs[dg * 8 + 1][p];
            float f2 = Xs[dg * 8 + 2][p], f3 = Xs[dg * 8 + 3][p];
            float f4 = Xs[dg * 8 + 4][p], f5 = Xs[dg * 8 + 5][p];
            float f6 = Xs[dg * 8 + 6][p], f7 = Xs[dg * 8 + 7][p];
            w0 = (u32)f2bf(f0) | ((u32)f2bf(f1) << 16);
            w1 = (u32)f2bf(f2) | ((u32)f2bf(f3) << 16);
            w2 = (u32)f2bf(f4) | ((u32)f2bf(f5) << 16);
            w3 = (u32)f2bf(f6) | ((u32)f2bf(f7) << 16);
        }
        uint4 ov = {w0, w1, w2, w3};
        *reinterpret_cast<uint4*>(Xh + (nbase + p) * 256 + c0 + dg * 8) = ov;
    }
}

// ---------------- prep E: transpose + split to bf16 hi/lo (small, 8 blocks)
__global__ __launch_bounds__(256) void prep_e(const float* __restrict__ src,
                                              u16* __restrict__ dH,
                                              u16* __restrict__ dL) {
    __shared__ float Xs[32][260];
    const int tid = threadIdx.x;
    const int p0 = blockIdx.x * 128;       // 8 blocks x 128 k
    for (int cc = 0; cc < 8; ++cc) {
#pragma unroll
        for (int r = 0; r < 4; ++r) {
            int id4 = tid + 256 * r;        // float4 id over [32][32]
            int c = id4 >> 5;
            int q = id4 & 31;
            float4 v = *reinterpret_cast<const float4*>(
                src + (size_t)(cc * 32 + c) * 1024 + p0 + q * 4);
            *reinterpret_cast<float4*>(&Xs[c][q * 4]) = v;
        }
        __syncthreads();
        // thread t: k = t & 127, half = t >> 7 handles 16 d's
        const int p = tid & 127;
        const int dh = (tid >> 7) * 16;
#pragma unroll
        for (int dg = 0; dg < 2; ++dg) {
            u32 hw[4], lw[4];
#pragma unroll
            for (int j2 = 0; j2 < 4; ++j2) {
                float fa = Xs[dh + dg * 8 + j2 * 2 + 0][p];
                float fb = Xs[dh + dg * 8 + j2 * 2 + 1][p];
                u16 ha = f2bf(fa), hb = f2bf(fb);
                u16 la = f2bf(fa - bf2f(ha)), lb = f2bf(fb - bf2f(hb));
                hw[j2] = (u32)ha | ((u32)hb << 16);
                lw[j2] = (u32)la | ((u32)lb << 16);
            }
            uint4 oh = {hw[0], hw[1], hw[2], hw[3]};
            uint4 ol = {lw[0], lw[1], lw[2], lw[3]};
            size_t o = (size_t)(p0 + p) * 256 + cc * 32 + dh + dg * 8;
            *reinterpret_cast<uint4*>(dH + o) = oh;
            *reinterpret_cast<uint4*>(dL + o) = ol;
        }
        __syncthreads();
    }
}

// esq in fp32 (for main) and fp64 (for repair)
__global__ __launch_bounds__(256) void esq_kernel(const float* __restrict__ E,
                                                  float* __restrict__ esq,
                                                  double* __restrict__ esqd) {
    int k = blockIdx.x * 256 + threadIdx.x;
    double s = 0.0;
#pragma unroll 8
    for (int c = 0; c < DCH; ++c) {
        double e = (double)E[c * KCB + k];
        s = fma(e, e, s);
    }
    esq[k] = (float)s;
    esqd[k] = s;
}

// ---------------- main: split-bf16 MFMA distance + fused top-2 argmin
#define BUFS  24576
#define EH_O  8192
#define EL_O  16384
#define ESQ_O 49152
#define MRG_O 53248
#define SM_SZ 56320

__global__ __launch_bounds__(256, 2) void vq_main_mfma(
        const u16* __restrict__ XhG, const u16* __restrict__ EhG,
        const u16* __restrict__ ElG, const float* __restrict__ esq,
        int* __restrict__ idx_out, int* __restrict__ flag_cnt,
        int* __restrict__ flag_list) {
    __shared__ alignas(16) char sm[SM_SZ];
    const int tid = threadIdx.x;
    const int l = tid & 63;
    const int w = tid >> 6;
    const int wm = w >> 1, wn = w & 1;
    const int pbase = blockIdx.x * 128;

    *reinterpret_cast<float4*>(sm + ESQ_O + tid * 16) =
        *reinterpret_cast<const float4*>(esq + tid * 4);

    const int rowt0 = w * 32 + (l >> 2);
    const int slog = (l & 3) ^ ((rowt0 >> 1) & 3);
    const char* XhB = reinterpret_cast<const char*>(XhG);
    const char* EhB = reinterpret_cast<const char*>(EhG);
    const char* ElB = reinterpret_cast<const char*>(ElG);
    const size_t xoff0 = (size_t)(pbase + rowt0) * 512 + slog * 16;
    const size_t eoff0 = (size_t)rowt0 * 512 + slog * 16;
    const int w2k = (w * 2) * 1024;

    const int rA = wm * 64 + (l & 15);
    const int addrA = rA * 64 + (((l >> 4) ^ ((rA >> 1) & 3)) * 16);
    const int rB = wn * 64 + (l & 15);
    const int addrB = rB * 64 + (((l >> 4) ^ ((rB >> 1) & 3)) * 16);

    auto STAGE = [&](int bufo, int nt, int dt) {
        size_t xo = xoff0 + (size_t)dt * 64;
        gl_lds16(XhB + xo,        sm + bufo + w2k);
        gl_lds16(XhB + xo + 8192, sm + bufo + w2k + 1024);
        size_t eo = eoff0 + (size_t)nt * 65536 + (size_t)dt * 64;
        gl_lds16(EhB + eo,        sm + bufo + EH_O + w2k);
        gl_lds16(EhB + eo + 8192, sm + bufo + EH_O + w2k + 1024);
        gl_lds16(ElB + eo,        sm + bufo + EL_O + w2k);
        gl_lds16(ElB + eo + 8192, sm + bufo + EL_O + w2k + 1024);
    };

    float b1[16], b2[16];
    int   i1[16];
#pragma unroll
    for (int q = 0; q < 16; ++q) { b1[q] = 3.4e38f; b2[q] = 3.4e38f; i1[q] = 0; }

    STAGE(0, 0, 0);
    __syncthreads();

    int step = 0;
    for (int nt = 0; nt < 8; ++nt) {
        f32x4 acc[4][4];
#pragma unroll
        for (int i = 0; i < 4; ++i)
#pragma unroll
            for (int j = 0; j < 4; ++j)
#pragma unroll
                for (int r = 0; r < 4; ++r) acc[i][j][r] = 0.f;

        for (int dt = 0; dt < 8; ++dt) {
            int nxt = step + 1;
            if (nxt < 64) STAGE((nxt & 1) * BUFS, nxt >> 3, nxt & 7);
            const char* bo = sm + (step & 1) * BUFS;
            s16x8 a[4], bh[4], bl[4];
#pragma unroll
            for (int i = 0; i < 4; ++i)
                a[i] = *reinterpret_cast<const s16x8*>(bo + addrA + i * 1024);
#pragma unroll
            for (int j = 0; j < 4; ++j) {
                bh[j] = *reinterpret_cast<const s16x8*>(bo + EH_O + addrB + j * 1024);
                bl[j] = *reinterpret_cast<const s16x8*>(bo + EL_O + addrB + j * 1024);
            }
#pragma unroll
            for (int i = 0; i < 4; ++i)
#pragma unroll
                for (int j = 0; j < 4; ++j) {
                    acc[i][j] = __builtin_amdgcn_mfma_f32_16x16x32_bf16(a[i], bh[j], acc[i][j], 0, 0, 0);
                    acc[i][j] = __builtin_amdgcn_mfma_f32_16x16x32_bf16(a[i], bl[j], acc[i][j], 0, 0, 0);
                }
            __syncthreads();
            ++step;
        }

        const int kb = nt * 128 + wn * 64 + (l & 15);
        float eq[4];
#pragma unroll
        for (int j = 0; j < 4; ++j)
            eq[j] = *reinterpret_cast<const float*>(sm + ESQ_O + (kb + j * 16) * 4);
#pragma unroll
        for (int i = 0; i < 4; ++i)
#pragma unroll
            for (int j = 0; j < 4; ++j)
#pragma unroll
                for (int r = 0; r < 4; ++r) {
                    float s = fmaf(-2.f, acc[i][j][r], eq[j]);
                    int ri = i * 4 + r;
                    bool lt = s < b1[ri];
                    b2[ri] = fminf(b2[ri], fmaxf(s, b1[ri]));
                    i1[ri] = lt ? (kb + j * 16) : i1[ri];
                    b1[ri] = fminf(b1[ri], s);
                }
    }

#pragma unroll
    for (int m = 1; m <= 8; m <<= 1) {
#pragma unroll
        for (int q = 0; q < 16; ++q) {
            float ob1 = __shfl_xor(b1[q], m);
            float ob2 = __shfl_xor(b2[q], m);
            int   oi  = __shfl_xor(i1[q], m);
            bool lt = ob1 < b1[q];
            b2[q] = fminf(fminf(b2[q], ob2), fmaxf(b1[q], ob1));
            i1[q] = lt ? oi : i1[q];
            b1[q] = fminf(b1[q], ob1);
        }
    }

    if ((l & 15) == 0) {
#pragma unroll
        for (int i = 0; i < 4; ++i)
#pragma unroll
            for (int r = 0; r < 4; ++r) {
                int q = i * 4 + r;
                int rl = wm * 64 + i * 16 + (l >> 4) * 4 + r;
                *reinterpret_cast<float*>(sm + MRG_O + (rl * 2 + wn) * 4) = b1[q];
                *reinterpret_cast<float*>(sm + MRG_O + 1024 + (rl * 2 + wn) * 4) = b2[q];
                *reinterpret_cast<int*>(sm + MRG_O + 2048 + (rl * 2 + wn) * 4) = i1[q];
            }
    }
    __syncthreads();
    if (tid < 128) {
        float a1 = *reinterpret_cast<float*>(sm + MRG_O + (tid * 2 + 0) * 4);
        float a2 = *reinterpret_cast<float*>(sm + MRG_O + 1024 + (tid * 2 + 0) * 4);
        int   ai = *reinterpret_cast<int*>(sm + MRG_O + 2048 + (tid * 2 + 0) * 4);
        float c1 = *reinterpret_cast<float*>(sm + MRG_O + (tid * 2 + 1) * 4);
        float c2 = *reinterpret_cast<float*>(sm + MRG_O + 1024 + (tid * 2 + 1) * 4);
        int   ci = *reinterpret_cast<int*>(sm + MRG_O + 2048 + (tid * 2 + 1) * 4);
        bool lt = c1 < a1;
        float B1 = fminf(a1, c1);
        float B2 = fminf(fminf(a2, c2), fmaxf(a1, c1));
        int I1 = lt ? ci : ai;
        int n = pbase + tid;
        idx_out[n] = I1;
        if (B2 - B1 < MARGIN) {
            int s2 = atomicAdd(flag_cnt, 1);
            flag_list[s2] = n;
        }
    }
}

// ---------------- exact fp64 re-scan, 4 flags per block, parallel
#define RFPB 4
__global__ __launch_bounds__(256) void vq_repair(const float* __restrict__ X,
                                                 const float* __restrict__ E,
                                                 const double* __restrict__ esqd,
                                                 int* __restrict__ idx_out,
                                                 const int* __restrict__ flag_cnt,
                                                 const int* __restrict__ flag_list) {
    __shared__ double xs[RFPB][256];
    __shared__ double rd[RFPB][256];
    __shared__ int    ri[RFPB][256];
    const int tid = threadIdx.x;
    const int cnt = *flag_cnt;
    for (int f0 = blockIdx.x * RFPB; f0 < cnt; f0 += gridDim.x * RFPB) {
#pragma unroll
        for (int g = 0; g < RFPB; ++g) {
            int f = f0 + g;
            int n = flag_list[f < cnt ? f : f0];
            int b = n >> 10, p = n & 1023;
            xs[g][tid] = (double)X[(size_t)b * 262144 + (size_t)tid * 1024 + p];
        }
        __syncthreads();
        double s[RFPB][4];
#pragma unroll
        for (int g = 0; g < RFPB; ++g)
#pragma unroll
            for (int j = 0; j < 4; ++j) s[g][j] = 0.0;
        const float4* Erow = reinterpret_cast<const float4*>(E) + tid;   // E[c][tid*4]
#pragma unroll 2
        for (int c = 0; c < 256; ++c) {
            float4 ev = Erow[c * 256];
            double e0 = (double)ev.x, e1 = (double)ev.y, e2 = (double)ev.z, e3 = (double)ev.w;
#pragma unroll
            for (int g = 0; g < RFPB; ++g) {
                double xv = xs[g][c];
                s[g][0] = fma(xv, e0, s[g][0]);
                s[g][1] = fma(xv, e1, s[g][1]);
                s[g][2] = fma(xv, e2, s[g][2]);
                s[g][3] = fma(xv, e3, s[g][3]);
            }
        }
        const int k0 = tid * 4;
        const double eq0 = esqd[k0], eq1 = esqd[k0 + 1], eq2 = esqd[k0 + 2], eq3 = esqd[k0 + 3];
#pragma unroll
        for (int g = 0; g < RFPB; ++g) {
            double d0 = eq0 - 2.0 * s[g][0];
            double d1 = eq1 - 2.0 * s[g][1];
            double d2 = eq2 - 2.0 * s[g][2];
            double d3 = eq3 - 2.0 * s[g][3];
            double bd = d0; int bi = k0;
            if (d1 < bd) { bd = d1; bi = k0 + 1; }
            if (d2 < bd) { bd = d2; bi = k0 + 2; }
            if (d3 < bd) { bd = d3; bi = k0 + 3; }
            rd[g][tid] = bd; ri[g][tid] = bi;
        }
        __syncthreads();
        for (int off = 128; off > 0; off >>= 1) {
            if (tid < off) {
#pragma unroll
                for (int g = 0; g < RFPB; ++g) {
                    double od = rd[g][tid + off]; int oi = ri[g][tid + off];
                    if (od < rd[g][tid] || (od == rd[g][tid] && oi < ri[g][tid])) {
                        rd[g][tid] = od; ri[g][tid] = oi;
                    }
                }
            }
            __syncthreads();
        }
        if (tid < RFPB && (f0 + tid) < cnt) {
            idx_out[flag_list[f0 + tid]] = ri[tid][0];
        }
        __syncthreads();
    }
}

// ---------------- gather + write outputs (LDS-staged E slice, coalesced)
#define WCC 8
__global__ __launch_bounds__(256) void vq_write(const float* __restrict__ E,
                                                const int* __restrict__ idx_ws,
                                                float* __restrict__ out0,
                                                float* __restrict__ out1,
                                                float* __restrict__ out2) {
    __shared__ float Es[WCC][1024];       // 32 KB
    const int tid = threadIdx.x;
    const int b   = blockIdx.x >> 5;      // 0..63
    const int cch = blockIdx.x & 31;      // 0..31 (8 c's each)
    // stage E slice [8 c][1024 k], coalesced
#pragma unroll
    for (int r = 0; r < 8; ++r) {
        int id4 = tid + 256 * r;          // float4 id over [8][256]
        int c = id4 >> 8;
        int q = id4 & 255;
        *reinterpret_cast<float4*>(&Es[c][q * 4]) =
            *reinterpret_cast<const float4*>(E + (size_t)(cch * WCC + c) * 1024 + q * 4);
    }
    int4 kv = *reinterpret_cast<const int4*>(idx_ws + b * 1024 + tid * 4);
    __syncthreads();
    if (cch == 0) {
        float4 v = {(float)kv.x, (float)kv.y, (float)kv.z, (float)kv.w};
        *reinterpret_cast<float4*>(out2 + b * 1024 + tid * 4) = v;
    }
#pragma unroll
    for (int c = 0; c < WCC; ++c) {
        float4 v = {Es[c][kv.x], Es[c][kv.y], Es[c][kv.z], Es[c][kv.w]};
        size_t o = (size_t)b * 262144 + (size_t)(cch * WCC + c) * 1024 + tid * 4;
        *reinterpret_cast<float4*>(out0 + o) = v;
        *reinterpret_cast<float4*>(out1 + o) = v;
    }
}

extern "C" void kernel_launch(void* const* d_in, const int* in_sizes, int n_in,
                              void* d_out, int out_size, void* d_ws, size_t ws_size,
                              hipStream_t stream) {
    const float* X = (const float*)d_in[0];   // [64,256,32,32] fp32
    const float* E = (const float*)d_in[1];   // [256,1024] fp32
    float* out = (float*)d_out;
    char* ws = (char*)d_ws;

    float* esq   = (float*)(ws + ESQ_WS);
    int* idx     = (int*)(ws + IDX_WS);
    int* fcnt    = (int*)(ws + FCNT_WS);
    int* flist   = (int*)(ws + FLIST_WS);
    double* esqd = (double*)(ws + ESQD_WS);
    u16* Xh      = (u16*)(ws + XH_WS);
    u16* Eh      = (u16*)(ws + EH_WS);
    u16* El      = (u16*)(ws + EL_WS);

    hipMemsetAsync(fcnt, 0, 4, stream);
    prep_x<<<2048, 256, 0, stream>>>(X, Xh);
    prep_e<<<8, 256, 0, stream>>>(E, Eh, El);
    esq_kernel<<<4, 256, 0, stream>>>(E, esq, esqd);
    vq_main_mfma<<<512, 256, 0, stream>>>(Xh, Eh, El, esq, idx, fcnt, flist);
    vq_repair<<<1024, 256, 0, stream>>>(X, E, esqd, idx, fcnt, flist);
    vq_write<<<2048, 256, 0, stream>>>(E, idx,
                                       out,                // q_ste
                                       out + 16777216,     // quantized
                                       out + 33554432);    // indices (as float)
}

// Round 5
// 178.256 us; speedup vs baseline: 3.6815x; 1.1699x over previous
//
#include <hip/hip_runtime.h>

typedef unsigned short u16;
typedef unsigned int   u32;

#define DCH  256
#define KCB  1024
#define HW   1024
#define NPOS 65536
#define MARGIN 0.12f

// ws layout (bytes)
#define ESQ_WS   0
#define IDX_WS   4096
#define FCNT_WS  266240
#define FLIST_WS 266304
#define ESQD_WS  528448ull             // double[1024] = 8 KB
#define XH_WS    1048576ull            // 65536*256 fp16 = 33.55 MB
#define EH_WS    34603008ull           // 1024*256 fp16 = 512 KB

using f32x4 = __attribute__((ext_vector_type(4))) float;
using f16x8 = __attribute__((ext_vector_type(8))) _Float16;

__device__ __forceinline__ u16 f2h(float x) {
    _Float16 h = (_Float16)x;          // RTN convert
    return *reinterpret_cast<u16*>(&h);
}

__device__ __forceinline__ void gl_lds16(const void* g, void* l) {
    __builtin_amdgcn_global_load_lds(
        (const __attribute__((address_space(1))) void*)g,
        (__attribute__((address_space(3))) void*)l, 16, 0, 0);
}

// ---------------- prep: transpose [256 c][1024 p] (one batch slice) -> dst[p][256 d] fp16
// fp32 padded-LDS transpose, bank-conflict-free. Used for X (grid 2048) and E (grid 32).
__global__ __launch_bounds__(256) void prep_x(const float* __restrict__ src,
                                              u16* __restrict__ dst) {
    __shared__ float Xs[32][260];     // pad 260 -> transpose reads are conflict-free
    const int tid = threadIdx.x;
    const int b  = blockIdx.x >> 5;
    const int pc = (blockIdx.x >> 3) & 3;   // 0..3
    const int cc = blockIdx.x & 7;          // 0..7
    const int p0 = pc * 256;
    const int c0 = cc * 32;
    const size_t nbase = (size_t)b * 1024 + p0;

    // stage [32 c][256 p] fp32, coalesced
#pragma unroll
    for (int r = 0; r < 8; ++r) {
        int id4 = tid + 256 * r;            // float4 id over [32][64]
        int c = id4 >> 6;
        int q = id4 & 63;
        float4 v = *reinterpret_cast<const float4*>(
            src + (size_t)b * 262144 + (size_t)(c0 + c) * 1024 + p0 + q * 4);
        *reinterpret_cast<float4*>(&Xs[c][q * 4]) = v;
    }
    __syncthreads();

    // transpose-read: thread t -> position p = t, produce 32 d's (4 x 16B)
    const int p = tid;
#pragma unroll
    for (int dg = 0; dg < 4; ++dg) {
        u32 w0, w1, w2, w3;
        {
            float f0 = Xs[dg * 8 + 0][p], f1 = Xs[dg * 8 + 1][p];
            float f2 = Xs[dg * 8 + 2][p], f3 = Xs[dg * 8 + 3][p];
            float f4 = Xs[dg * 8 + 4][p], f5 = Xs[dg * 8 + 5][p];
            float f6 = Xs[dg * 8 + 6][p], f7 = Xs[dg * 8 + 7][p];
            w0 = (u32)f2h(f0) | ((u32)f2h(f1) << 16);
            w1 = (u32)f2h(f2) | ((u32)f2h(f3) << 16);
            w2 = (u32)f2h(f4) | ((u32)f2h(f5) << 16);
            w3 = (u32)f2h(f6) | ((u32)f2h(f7) << 16);
        }
        uint4 ov = {w0, w1, w2, w3};
        *reinterpret_cast<uint4*>(dst + (nbase + p) * 256 + c0 + dg * 8) = ov;
    }
}

// esq in fp32 (for main) and fp64 (for repair) from exact fp32 E
__global__ __launch_bounds__(256) void esq_kernel(const float* __restrict__ E,
                                                  float* __restrict__ esq,
                                                  double* __restrict__ esqd) {
    int k = blockIdx.x * 256 + threadIdx.x;
    double s = 0.0;
#pragma unroll 8
    for (int c = 0; c < DCH; ++c) {
        double e = (double)E[c * KCB + k];
        s = fma(e, e, s);
    }
    esq[k] = (float)s;
    esqd[k] = s;
}

// ---------------- main: fp16 single-stream MFMA distance + fused top-2 argmin
#define BUFS  16384
#define EH_O  8192
#define ESQ_O 32768
#define MRG_O 36864
#define SM_SZ 39936

__global__ __launch_bounds__(256, 2) void vq_main_mfma(
        const u16* __restrict__ XhG, const u16* __restrict__ EhG,
        const float* __restrict__ esq,
        int* __restrict__ idx_out, int* __restrict__ flag_cnt,
        int* __restrict__ flag_list) {
    __shared__ alignas(16) char sm[SM_SZ];
    const int tid = threadIdx.x;
    const int l = tid & 63;
    const int w = tid >> 6;
    const int wm = w >> 1, wn = w & 1;
    const int pbase = blockIdx.x * 128;

    *reinterpret_cast<float4*>(sm + ESQ_O + tid * 16) =
        *reinterpret_cast<const float4*>(esq + tid * 4);

    const int rowt0 = w * 32 + (l >> 2);
    const int slog = (l & 3) ^ ((rowt0 >> 1) & 3);
    const char* XhB = reinterpret_cast<const char*>(XhG);
    const char* EhB = reinterpret_cast<const char*>(EhG);
    const size_t xoff0 = (size_t)(pbase + rowt0) * 512 + slog * 16;
    const size_t eoff0 = (size_t)rowt0 * 512 + slog * 16;
    const int w2k = (w * 2) * 1024;

    const int rA = wm * 64 + (l & 15);
    const int addrA = rA * 64 + (((l >> 4) ^ ((rA >> 1) & 3)) * 16);
    const int rB = wn * 64 + (l & 15);
    const int addrB = rB * 64 + (((l >> 4) ^ ((rB >> 1) & 3)) * 16);

    auto STAGE = [&](int bufo, int nt, int dt) {
        size_t xo = xoff0 + (size_t)dt * 64;
        gl_lds16(XhB + xo,        sm + bufo + w2k);
        gl_lds16(XhB + xo + 8192, sm + bufo + w2k + 1024);
        size_t eo = eoff0 + (size_t)nt * 65536 + (size_t)dt * 64;
        gl_lds16(EhB + eo,        sm + bufo + EH_O + w2k);
        gl_lds16(EhB + eo + 8192, sm + bufo + EH_O + w2k + 1024);
    };

    float b1[16], b2[16];
    int   i1[16];
#pragma unroll
    for (int q = 0; q < 16; ++q) { b1[q] = 3.4e38f; b2[q] = 3.4e38f; i1[q] = 0; }

    STAGE(0, 0, 0);
    __syncthreads();

    int step = 0;
    for (int nt = 0; nt < 8; ++nt) {
        f32x4 acc[4][4];
#pragma unroll
        for (int i = 0; i < 4; ++i)
#pragma unroll
            for (int j = 0; j < 4; ++j)
#pragma unroll
                for (int r = 0; r < 4; ++r) acc[i][j][r] = 0.f;

        for (int dt = 0; dt < 8; ++dt) {
            int nxt = step + 1;
            if (nxt < 64) STAGE((nxt & 1) * BUFS, nxt >> 3, nxt & 7);
            const char* bo = sm + (step & 1) * BUFS;
            f16x8 a[4], bh[4];
#pragma unroll
            for (int i = 0; i < 4; ++i)
                a[i] = *reinterpret_cast<const f16x8*>(bo + addrA + i * 1024);
#pragma unroll
            for (int j = 0; j < 4; ++j)
                bh[j] = *reinterpret_cast<const f16x8*>(bo + EH_O + addrB + j * 1024);
#pragma unroll
            for (int i = 0; i < 4; ++i)
#pragma unroll
                for (int j = 0; j < 4; ++j)
                    acc[i][j] = __builtin_amdgcn_mfma_f32_16x16x32_f16(a[i], bh[j], acc[i][j], 0, 0, 0);
            __syncthreads();
            ++step;
        }

        const int kb = nt * 128 + wn * 64 + (l & 15);
        float eq[4];
#pragma unroll
        for (int j = 0; j < 4; ++j)
            eq[j] = *reinterpret_cast<const float*>(sm + ESQ_O + (kb + j * 16) * 4);
#pragma unroll
        for (int i = 0; i < 4; ++i)
#pragma unroll
            for (int j = 0; j < 4; ++j)
#pragma unroll
                for (int r = 0; r < 4; ++r) {
                    float s = fmaf(-2.f, acc[i][j][r], eq[j]);
                    int ri = i * 4 + r;
                    bool lt = s < b1[ri];
                    b2[ri] = fminf(b2[ri], fmaxf(s, b1[ri]));
                    i1[ri] = lt ? (kb + j * 16) : i1[ri];
                    b1[ri] = fminf(b1[ri], s);
                }
    }

#pragma unroll
    for (int m = 1; m <= 8; m <<= 1) {
#pragma unroll
        for (int q = 0; q < 16; ++q) {
            float ob1 = __shfl_xor(b1[q], m);
            float ob2 = __shfl_xor(b2[q], m);
            int   oi  = __shfl_xor(i1[q], m);
            bool lt = ob1 < b1[q];
            b2[q] = fminf(fminf(b2[q], ob2), fmaxf(b1[q], ob1));
            i1[q] = lt ? oi : i1[q];
            b1[q] = fminf(b1[q], ob1);
        }
    }

    if ((l & 15) == 0) {
#pragma unroll
        for (int i = 0; i < 4; ++i)
#pragma unroll
            for (int r = 0; r < 4; ++r) {
                int q = i * 4 + r;
                int rl = wm * 64 + i * 16 + (l >> 4) * 4 + r;
                *reinterpret_cast<float*>(sm + MRG_O + (rl * 2 + wn) * 4) = b1[q];
                *reinterpret_cast<float*>(sm + MRG_O + 1024 + (rl * 2 + wn) * 4) = b2[q];
                *reinterpret_cast<int*>(sm + MRG_O + 2048 + (rl * 2 + wn) * 4) = i1[q];
            }
    }
    __syncthreads();
    if (tid < 128) {
        float a1 = *reinterpret_cast<float*>(sm + MRG_O + (tid * 2 + 0) * 4);
        float a2 = *reinterpret_cast<float*>(sm + MRG_O + 1024 + (tid * 2 + 0) * 4);
        int   ai = *reinterpret_cast<int*>(sm + MRG_O + 2048 + (tid * 2 + 0) * 4);
        float c1 = *reinterpret_cast<float*>(sm + MRG_O + (tid * 2 + 1) * 4);
        float c2 = *reinterpret_cast<float*>(sm + MRG_O + 1024 + (tid * 2 + 1) * 4);
        int   ci = *reinterpret_cast<int*>(sm + MRG_O + 2048 + (tid * 2 + 1) * 4);
        bool lt = c1 < a1;
        float B1 = fminf(a1, c1);
        float B2 = fminf(fminf(a2, c2), fmaxf(a1, c1));
        int I1 = lt ? ci : ai;
        int n = pbase + tid;
        idx_out[n] = I1;
        if (B2 - B1 < MARGIN) {
            int s2 = atomicAdd(flag_cnt, 1);
            flag_list[s2] = n;
        }
    }
}

// ---------------- exact fp64 re-scan, 4 flags per block, parallel
#define RFPB 4
__global__ __launch_bounds__(256) void vq_repair(const float* __restrict__ X,
                                                 const float* __restrict__ E,
                                                 const double* __restrict__ esqd,
                                                 int* __restrict__ idx_out,
                                                 const int* __restrict__ flag_cnt,
                                                 const int* __restrict__ flag_list) {
    __shared__ double xs[RFPB][256];
    __shared__ double rd[RFPB][256];
    __shared__ int    ri[RFPB][256];
    const int tid = threadIdx.x;
    const int cnt = *flag_cnt;
    for (int f0 = blockIdx.x * RFPB; f0 < cnt; f0 += gridDim.x * RFPB) {
#pragma unroll
        for (int g = 0; g < RFPB; ++g) {
            int f = f0 + g;
            int n = flag_list[f < cnt ? f : f0];
            int b = n >> 10, p = n & 1023;
            xs[g][tid] = (double)X[(size_t)b * 262144 + (size_t)tid * 1024 + p];
        }
        __syncthreads();
        double s[RFPB][4];
#pragma unroll
        for (int g = 0; g < RFPB; ++g)
#pragma unroll
            for (int j = 0; j < 4; ++j) s[g][j] = 0.0;
        const float4* Erow = reinterpret_cast<const float4*>(E) + tid;   // E[c][tid*4]
#pragma unroll 2
        for (int c = 0; c < 256; ++c) {
            float4 ev = Erow[c * 256];
            double e0 = (double)ev.x, e1 = (double)ev.y, e2 = (double)ev.z, e3 = (double)ev.w;
#pragma unroll
            for (int g = 0; g < RFPB; ++g) {
                double xv = xs[g][c];
                s[g][0] = fma(xv, e0, s[g][0]);
                s[g][1] = fma(xv, e1, s[g][1]);
                s[g][2] = fma(xv, e2, s[g][2]);
                s[g][3] = fma(xv, e3, s[g][3]);
            }
        }
        const int k0 = tid * 4;
        const double eq0 = esqd[k0], eq1 = esqd[k0 + 1], eq2 = esqd[k0 + 2], eq3 = esqd[k0 + 3];
#pragma unroll
        for (int g = 0; g < RFPB; ++g) {
            double d0 = eq0 - 2.0 * s[g][0];
            double d1 = eq1 - 2.0 * s[g][1];
            double d2 = eq2 - 2.0 * s[g][2];
            double d3 = eq3 - 2.0 * s[g][3];
            double bd = d0; int bi = k0;
            if (d1 < bd) { bd = d1; bi = k0 + 1; }
            if (d2 < bd) { bd = d2; bi = k0 + 2; }
            if (d3 < bd) { bd = d3; bi = k0 + 3; }
            rd[g][tid] = bd; ri[g][tid] = bi;
        }
        __syncthreads();
        for (int off = 128; off > 0; off >>= 1) {
            if (tid < off) {
#pragma unroll
                for (int g = 0; g < RFPB; ++g) {
                    double od = rd[g][tid + off]; int oi = ri[g][tid + off];
                    if (od < rd[g][tid] || (od == rd[g][tid] && oi < ri[g][tid])) {
                        rd[g][tid] = od; ri[g][tid] = oi;
                    }
                }
            }
            __syncthreads();
        }
        if (tid < RFPB && (f0 + tid) < cnt) {
            idx_out[flag_list[f0 + tid]] = ri[tid][0];
        }
        __syncthreads();
    }
}

// ---------------- gather + write outputs (LDS-staged E slice, coalesced)
#define WCC 8
__global__ __launch_bounds__(256) void vq_write(const float* __restrict__ E,
                                                const int* __restrict__ idx_ws,
                                                float* __restrict__ out0,
                                                float* __restrict__ out1,
                                                float* __restrict__ out2) {
    __shared__ float Es[WCC][1024];       // 32 KB
    const int tid = threadIdx.x;
    const int b   = blockIdx.x >> 5;      // 0..63
    const int cch = blockIdx.x & 31;      // 0..31 (8 c's each)
#pragma unroll
    for (int r = 0; r < 8; ++r) {
        int id4 = tid + 256 * r;          // float4 id over [8][256]
        int c = id4 >> 8;
        int q = id4 & 255;
        *reinterpret_cast<float4*>(&Es[c][q * 4]) =
            *reinterpret_cast<const float4*>(E + (size_t)(cch * WCC + c) * 1024 + q * 4);
    }
    int4 kv = *reinterpret_cast<const int4*>(idx_ws + b * 1024 + tid * 4);
    __syncthreads();
    if (cch == 0) {
        float4 v = {(float)kv.x, (float)kv.y, (float)kv.z, (float)kv.w};
        *reinterpret_cast<float4*>(out2 + b * 1024 + tid * 4) = v;
    }
#pragma unroll
    for (int c = 0; c < WCC; ++c) {
        float4 v = {Es[c][kv.x], Es[c][kv.y], Es[c][kv.z], Es[c][kv.w]};
        size_t o = (size_t)b * 262144 + (size_t)(cch * WCC + c) * 1024 + tid * 4;
        *reinterpret_cast<float4*>(out0 + o) = v;
        *reinterpret_cast<float4*>(out1 + o) = v;
    }
}

extern "C" void kernel_launch(void* const* d_in, const int* in_sizes, int n_in,
                              void* d_out, int out_size, void* d_ws, size_t ws_size,
                              hipStream_t stream) {
    const float* X = (const float*)d_in[0];   // [64,256,32,32] fp32
    const float* E = (const float*)d_in[1];   // [256,1024] fp32
    float* out = (float*)d_out;
    char* ws = (char*)d_ws;

    float* esq   = (float*)(ws + ESQ_WS);
    int* idx     = (int*)(ws + IDX_WS);
    int* fcnt    = (int*)(ws + FCNT_WS);
    int* flist   = (int*)(ws + FLIST_WS);
    double* esqd = (double*)(ws + ESQD_WS);
    u16* Xh      = (u16*)(ws + XH_WS);
    u16* Eh      = (u16*)(ws + EH_WS);

    hipMemsetAsync(fcnt, 0, 4, stream);
    prep_x<<<2048, 256, 0, stream>>>(X, Xh);
    prep_x<<<32, 256, 0, stream>>>(E, Eh);     // E is one [256][1024] slice
    esq_kernel<<<4, 256, 0, stream>>>(E, esq, esqd);
    vq_main_mfma<<<512, 256, 0, stream>>>(Xh, Eh, esq, idx, fcnt, flist);
    vq_repair<<<1024, 256, 0, stream>>>(X, E, esqd, idx, fcnt, flist);
    vq_write<<<2048, 256, 0, stream>>>(E, idx,
                                       out,                // q_ste
                                       out + 16777216,     // quantized
                                       out + 33554432);    // indices (as float)
}

// Round 6
// 172.774 us; speedup vs baseline: 3.7983x; 1.0317x over previous
//
#include <hip/hip_runtime.h>

typedef unsigned short u16;
typedef unsigned int   u32;

#define DCH  256
#define KCB  1024
#define HW   1024
#define NPOS 65536
#define MARGIN 0.12f

// ws layout (bytes)
#define ESQ_WS   0
#define IDX_WS   4096
#define FCNT_WS  266240
#define FLIST_WS 266304
#define ESQD_WS  528448ull             // double[1024] = 8 KB
#define XH_WS    1048576ull            // 65536*256 fp16 = 33.55 MB
#define EH_WS    34603008ull           // 1024*256 fp16 = 512 KB

using f32x4 = __attribute__((ext_vector_type(4))) float;
using f16x8 = __attribute__((ext_vector_type(8))) _Float16;

__device__ __forceinline__ u16 f2h(float x) {
    _Float16 h = (_Float16)x;          // RTN convert
    return *reinterpret_cast<u16*>(&h);
}

__device__ __forceinline__ void gl_lds16(const void* g, void* l) {
    __builtin_amdgcn_global_load_lds(
        (const __attribute__((address_space(1))) void*)g,
        (__attribute__((address_space(3))) void*)l, 16, 0, 0);
}

// ---------------- prep: transpose [256 c][1024 p] (one batch slice) -> dst[p][256 d] fp16
// fp32 padded-LDS transpose, bank-conflict-free. Used for X (grid 2048) and E (grid 32).
// Also zeroes flag_cnt from block 0 (replaces a pathologically slow graph memset node).
__global__ __launch_bounds__(256) void prep_x(const float* __restrict__ src,
                                              u16* __restrict__ dst,
                                              int* __restrict__ fcnt) {
    __shared__ float Xs[32][260];     // pad 260 -> transpose reads are conflict-free
    const int tid = threadIdx.x;
    if (blockIdx.x == 0 && tid == 0) *fcnt = 0;
    const int b  = blockIdx.x >> 5;
    const int pc = (blockIdx.x >> 3) & 3;   // 0..3
    const int cc = blockIdx.x & 7;          // 0..7
    const int p0 = pc * 256;
    const int c0 = cc * 32;
    const size_t nbase = (size_t)b * 1024 + p0;

    // stage [32 c][256 p] fp32, coalesced
#pragma unroll
    for (int r = 0; r < 8; ++r) {
        int id4 = tid + 256 * r;            // float4 id over [32][64]
        int c = id4 >> 6;
        int q = id4 & 63;
        float4 v = *reinterpret_cast<const float4*>(
            src + (size_t)b * 262144 + (size_t)(c0 + c) * 1024 + p0 + q * 4);
        *reinterpret_cast<float4*>(&Xs[c][q * 4]) = v;
    }
    __syncthreads();

    // transpose-read: thread t -> position p = t, produce 32 d's (4 x 16B)
    const int p = tid;
#pragma unroll
    for (int dg = 0; dg < 4; ++dg) {
        u32 w0, w1, w2, w3;
        {
            float f0 = Xs[dg * 8 + 0][p], f1 = Xs[dg * 8 + 1][p];
            float f2 = Xs[dg * 8 + 2][p], f3 = Xs[dg * 8 + 3][p];
            float f4 = Xs[dg * 8 + 4][p], f5 = Xs[dg * 8 + 5][p];
            float f6 = Xs[dg * 8 + 6][p], f7 = Xs[dg * 8 + 7][p];
            w0 = (u32)f2h(f0) | ((u32)f2h(f1) << 16);
            w1 = (u32)f2h(f2) | ((u32)f2h(f3) << 16);
            w2 = (u32)f2h(f4) | ((u32)f2h(f5) << 16);
            w3 = (u32)f2h(f6) | ((u32)f2h(f7) << 16);
        }
        uint4 ov = {w0, w1, w2, w3};
        *reinterpret_cast<uint4*>(dst + (nbase + p) * 256 + c0 + dg * 8) = ov;
    }
}

// esq in fp32 (for main) and fp64 (for repair) from exact fp32 E
__global__ __launch_bounds__(256) void esq_kernel(const float* __restrict__ E,
                                                  float* __restrict__ esq,
                                                  double* __restrict__ esqd) {
    int k = blockIdx.x * 256 + threadIdx.x;
    double s = 0.0;
#pragma unroll 8
    for (int c = 0; c < DCH; ++c) {
        double e = (double)E[c * KCB + k];
        s = fma(e, e, s);
    }
    esq[k] = (float)s;
    esqd[k] = s;
}

// ---------------- main: fp16 single-stream MFMA distance + fused top-2 argmin
#define BUFS  16384
#define EH_O  8192
#define ESQ_O 32768
#define MRG_O 36864
#define SM_SZ 39936

__global__ __launch_bounds__(256, 2) void vq_main_mfma(
        const u16* __restrict__ XhG, const u16* __restrict__ EhG,
        const float* __restrict__ esq,
        int* __restrict__ idx_out, int* __restrict__ flag_cnt,
        int* __restrict__ flag_list) {
    __shared__ alignas(16) char sm[SM_SZ];
    const int tid = threadIdx.x;
    const int l = tid & 63;
    const int w = tid >> 6;
    const int wm = w >> 1, wn = w & 1;
    const int pbase = blockIdx.x * 128;

    *reinterpret_cast<float4*>(sm + ESQ_O + tid * 16) =
        *reinterpret_cast<const float4*>(esq + tid * 4);

    const int rowt0 = w * 32 + (l >> 2);
    const int slog = (l & 3) ^ ((rowt0 >> 1) & 3);
    const char* XhB = reinterpret_cast<const char*>(XhG);
    const char* EhB = reinterpret_cast<const char*>(EhG);
    const size_t xoff0 = (size_t)(pbase + rowt0) * 512 + slog * 16;
    const size_t eoff0 = (size_t)rowt0 * 512 + slog * 16;
    const int w2k = (w * 2) * 1024;

    const int rA = wm * 64 + (l & 15);
    const int addrA = rA * 64 + (((l >> 4) ^ ((rA >> 1) & 3)) * 16);
    const int rB = wn * 64 + (l & 15);
    const int addrB = rB * 64 + (((l >> 4) ^ ((rB >> 1) & 3)) * 16);

    auto STAGE = [&](int bufo, int nt, int dt) {
        size_t xo = xoff0 + (size_t)dt * 64;
        gl_lds16(XhB + xo,        sm + bufo + w2k);
        gl_lds16(XhB + xo + 8192, sm + bufo + w2k + 1024);
        size_t eo = eoff0 + (size_t)nt * 65536 + (size_t)dt * 64;
        gl_lds16(EhB + eo,        sm + bufo + EH_O + w2k);
        gl_lds16(EhB + eo + 8192, sm + bufo + EH_O + w2k + 1024);
    };

    float b1[16], b2[16];
    int   i1[16];
#pragma unroll
    for (int q = 0; q < 16; ++q) { b1[q] = 3.4e38f; b2[q] = 3.4e38f; i1[q] = 0; }

    STAGE(0, 0, 0);
    __syncthreads();

    int step = 0;
    for (int nt = 0; nt < 8; ++nt) {
        f32x4 acc[4][4];
#pragma unroll
        for (int i = 0; i < 4; ++i)
#pragma unroll
            for (int j = 0; j < 4; ++j)
#pragma unroll
                for (int r = 0; r < 4; ++r) acc[i][j][r] = 0.f;

        for (int dt = 0; dt < 8; ++dt) {
            int nxt = step + 1;
            if (nxt < 64) STAGE((nxt & 1) * BUFS, nxt >> 3, nxt & 7);
            const char* bo = sm + (step & 1) * BUFS;
            f16x8 a[4], bh[4];
#pragma unroll
            for (int i = 0; i < 4; ++i)
                a[i] = *reinterpret_cast<const f16x8*>(bo + addrA + i * 1024);
#pragma unroll
            for (int j = 0; j < 4; ++j)
                bh[j] = *reinterpret_cast<const f16x8*>(bo + EH_O + addrB + j * 1024);
#pragma unroll
            for (int i = 0; i < 4; ++i)
#pragma unroll
                for (int j = 0; j < 4; ++j)
                    acc[i][j] = __builtin_amdgcn_mfma_f32_16x16x32_f16(a[i], bh[j], acc[i][j], 0, 0, 0);
            __syncthreads();
            ++step;
        }

        const int kb = nt * 128 + wn * 64 + (l & 15);
        float eq[4];
#pragma unroll
        for (int j = 0; j < 4; ++j)
            eq[j] = *reinterpret_cast<const float*>(sm + ESQ_O + (kb + j * 16) * 4);
#pragma unroll
        for (int i = 0; i < 4; ++i)
#pragma unroll
            for (int j = 0; j < 4; ++j)
#pragma unroll
                for (int r = 0; r < 4; ++r) {
                    float s = fmaf(-2.f, acc[i][j][r], eq[j]);
                    int ri = i * 4 + r;
                    bool lt = s < b1[ri];
                    b2[ri] = fminf(b2[ri], fmaxf(s, b1[ri]));
                    i1[ri] = lt ? (kb + j * 16) : i1[ri];
                    b1[ri] = fminf(b1[ri], s);
                }
    }

#pragma unroll
    for (int m = 1; m <= 8; m <<= 1) {
#pragma unroll
        for (int q = 0; q < 16; ++q) {
            float ob1 = __shfl_xor(b1[q], m);
            float ob2 = __shfl_xor(b2[q], m);
            int   oi  = __shfl_xor(i1[q], m);
            bool lt = ob1 < b1[q];
            b2[q] = fminf(fminf(b2[q], ob2), fmaxf(b1[q], ob1));
            i1[q] = lt ? oi : i1[q];
            b1[q] = fminf(b1[q], ob1);
        }
    }

    if ((l & 15) == 0) {
#pragma unroll
        for (int i = 0; i < 4; ++i)
#pragma unroll
            for (int r = 0; r < 4; ++r) {
                int q = i * 4 + r;
                int rl = wm * 64 + i * 16 + (l >> 4) * 4 + r;
                *reinterpret_cast<float*>(sm + MRG_O + (rl * 2 + wn) * 4) = b1[q];
                *reinterpret_cast<float*>(sm + MRG_O + 1024 + (rl * 2 + wn) * 4) = b2[q];
                *reinterpret_cast<int*>(sm + MRG_O + 2048 + (rl * 2 + wn) * 4) = i1[q];
            }
    }
    __syncthreads();
    if (tid < 128) {
        float a1 = *reinterpret_cast<float*>(sm + MRG_O + (tid * 2 + 0) * 4);
        float a2 = *reinterpret_cast<float*>(sm + MRG_O + 1024 + (tid * 2 + 0) * 4);
        int   ai = *reinterpret_cast<int*>(sm + MRG_O + 2048 + (tid * 2 + 0) * 4);
        float c1 = *reinterpret_cast<float*>(sm + MRG_O + (tid * 2 + 1) * 4);
        float c2 = *reinterpret_cast<float*>(sm + MRG_O + 1024 + (tid * 2 + 1) * 4);
        int   ci = *reinterpret_cast<int*>(sm + MRG_O + 2048 + (tid * 2 + 1) * 4);
        bool lt = c1 < a1;
        float B1 = fminf(a1, c1);
        float B2 = fminf(fminf(a2, c2), fmaxf(a1, c1));
        int I1 = lt ? ci : ai;
        int n = pbase + tid;
        idx_out[n] = I1;
        if (B2 - B1 < MARGIN) {
            int s2 = atomicAdd(flag_cnt, 1);
            flag_list[s2] = n;
        }
    }
}

// ---------------- exact fp64 re-scan, 4 flags per block, parallel
#define RFPB 4
__global__ __launch_bounds__(256) void vq_repair(const float* __restrict__ X,
                                                 const float* __restrict__ E,
                                                 const double* __restrict__ esqd,
                                                 int* __restrict__ idx_out,
                                                 const int* __restrict__ flag_cnt,
                                                 const int* __restrict__ flag_list) {
    __shared__ double xs[RFPB][256];
    __shared__ double rd[RFPB][256];
    __shared__ int    ri[RFPB][256];
    const int tid = threadIdx.x;
    const int cnt = *flag_cnt;
    for (int f0 = blockIdx.x * RFPB; f0 < cnt; f0 += gridDim.x * RFPB) {
#pragma unroll
        for (int g = 0; g < RFPB; ++g) {
            int f = f0 + g;
            int n = flag_list[f < cnt ? f : f0];
            int b = n >> 10, p = n & 1023;
            xs[g][tid] = (double)X[(size_t)b * 262144 + (size_t)tid * 1024 + p];
        }
        __syncthreads();
        double s[RFPB][4];
#pragma unroll
        for (int g = 0; g < RFPB; ++g)
#pragma unroll
            for (int j = 0; j < 4; ++j) s[g][j] = 0.0;
        const float4* Erow = reinterpret_cast<const float4*>(E) + tid;   // E[c][tid*4]
#pragma unroll 2
        for (int c = 0; c < 256; ++c) {
            float4 ev = Erow[c * 256];
            double e0 = (double)ev.x, e1 = (double)ev.y, e2 = (double)ev.z, e3 = (double)ev.w;
#pragma unroll
            for (int g = 0; g < RFPB; ++g) {
                double xv = xs[g][c];
                s[g][0] = fma(xv, e0, s[g][0]);
                s[g][1] = fma(xv, e1, s[g][1]);
                s[g][2] = fma(xv, e2, s[g][2]);
                s[g][3] = fma(xv, e3, s[g][3]);
            }
        }
        const int k0 = tid * 4;
        const double eq0 = esqd[k0], eq1 = esqd[k0 + 1], eq2 = esqd[k0 + 2], eq3 = esqd[k0 + 3];
#pragma unroll
        for (int g = 0; g < RFPB; ++g) {
            double d0 = eq0 - 2.0 * s[g][0];
            double d1 = eq1 - 2.0 * s[g][1];
            double d2 = eq2 - 2.0 * s[g][2];
            double d3 = eq3 - 2.0 * s[g][3];
            double bd = d0; int bi = k0;
            if (d1 < bd) { bd = d1; bi = k0 + 1; }
            if (d2 < bd) { bd = d2; bi = k0 + 2; }
            if (d3 < bd) { bd = d3; bi = k0 + 3; }
            rd[g][tid] = bd; ri[g][tid] = bi;
        }
        __syncthreads();
        for (int off = 128; off > 0; off >>= 1) {
            if (tid < off) {
#pragma unroll
                for (int g = 0; g < RFPB; ++g) {
                    double od = rd[g][tid + off]; int oi = ri[g][tid + off];
                    if (od < rd[g][tid] || (od == rd[g][tid] && oi < ri[g][tid])) {
                        rd[g][tid] = od; ri[g][tid] = oi;
                    }
                }
            }
            __syncthreads();
        }
        if (tid < RFPB && (f0 + tid) < cnt) {
            idx_out[flag_list[f0 + tid]] = ri[tid][0];
        }
        __syncthreads();
    }
}

// ---------------- gather + write outputs (LDS-staged E slice, coalesced)
#define WCC 8
__global__ __launch_bounds__(256) void vq_write(const float* __restrict__ E,
                                                const int* __restrict__ idx_ws,
                                                float* __restrict__ out0,
                                                float* __restrict__ out1,
                                                float* __restrict__ out2) {
    __shared__ float Es[WCC][1024];       // 32 KB
    const int tid = threadIdx.x;
    const int b   = blockIdx.x >> 5;      // 0..63
    const int cch = blockIdx.x & 31;      // 0..31 (8 c's each)
#pragma unroll
    for (int r = 0; r < 8; ++r) {
        int id4 = tid + 256 * r;          // float4 id over [8][256]
        int c = id4 >> 8;
        int q = id4 & 255;
        *reinterpret_cast<float4*>(&Es[c][q * 4]) =
            *reinterpret_cast<const float4*>(E + (size_t)(cch * WCC + c) * 1024 + q * 4);
    }
    int4 kv = *reinterpret_cast<const int4*>(idx_ws + b * 1024 + tid * 4);
    __syncthreads();
    if (cch == 0) {
        float4 v = {(float)kv.x, (float)kv.y, (float)kv.z, (float)kv.w};
        *reinterpret_cast<float4*>(out2 + b * 1024 + tid * 4) = v;
    }
#pragma unroll
    for (int c = 0; c < WCC; ++c) {
        float4 v = {Es[c][kv.x], Es[c][kv.y], Es[c][kv.z], Es[c][kv.w]};
        size_t o = (size_t)b * 262144 + (size_t)(cch * WCC + c) * 1024 + tid * 4;
        *reinterpret_cast<float4*>(out0 + o) = v;
        *reinterpret_cast<float4*>(out1 + o) = v;
    }
}

extern "C" void kernel_launch(void* const* d_in, const int* in_sizes, int n_in,
                              void* d_out, int out_size, void* d_ws, size_t ws_size,
                              hipStream_t stream) {
    const float* X = (const float*)d_in[0];   // [64,256,32,32] fp32
    const float* E = (const float*)d_in[1];   // [256,1024] fp32
    float* out = (float*)d_out;
    char* ws = (char*)d_ws;

    float* esq   = (float*)(ws + ESQ_WS);
    int* idx     = (int*)(ws + IDX_WS);
    int* fcnt    = (int*)(ws + FCNT_WS);
    int* flist   = (int*)(ws + FLIST_WS);
    double* esqd = (double*)(ws + ESQD_WS);
    u16* Xh      = (u16*)(ws + XH_WS);
    u16* Eh      = (u16*)(ws + EH_WS);

    prep_x<<<2048, 256, 0, stream>>>(X, Xh, fcnt);   // also zeroes fcnt (block 0)
    prep_x<<<32, 256, 0, stream>>>(E, Eh, fcnt);     // E is one [256][1024] slice
    esq_kernel<<<4, 256, 0, stream>>>(E, esq, esqd);
    vq_main_mfma<<<512, 256, 0, stream>>>(Xh, Eh, esq, idx, fcnt, flist);
    vq_repair<<<1024, 256, 0, stream>>>(X, E, esqd, idx, fcnt, flist);
    vq_write<<<2048, 256, 0, stream>>>(E, idx,
                                       out,                // q_ste
                                       out + 16777216,     // quantized
                                       out + 33554432);    // indices (as float)
}